// Round 1
// 1536.613 us; speedup vs baseline: 1.0553x; 1.0553x over previous
//
#include <hip/hip_runtime.h>

// ---------------------------------------------------------------------------
// ResAttentionBlock: out = x + (y@v_w^T + v_b) * cos_sim_per_head(q_gather, y@k_w^T + k_b)
//   where q = rmsnorm(x) @ q_w^T + q_b, gathered by x_replica.
// GEMM v2: 128x128 tile, BK=64, double-buffered LDS with counted vmcnt(8)
// prefetch (T3/T4-lite), XOR bank-swizzle on both stage-source and ds_read
// (T2 / G4), XCD-aware block remap so the 8 col-blocks of each A row-panel
// share one XCD's L2 (T1). N=65536, H=1024, 16 heads x 64.
// ---------------------------------------------------------------------------

typedef unsigned short u16;
typedef unsigned int u32;
typedef __attribute__((ext_vector_type(4))) unsigned short u16x4;
typedef __attribute__((ext_vector_type(8))) short short8;   // 8 bf16 in 4 VGPRs
typedef __attribute__((ext_vector_type(4))) float floatx4;

#define NROW 65536
#define HID  1024

__device__ __forceinline__ u16 f2bf(float f) {
  union { float f; u32 u; } v; v.f = f;
  u32 r = v.u + 0x7fffu + ((v.u >> 16) & 1u);   // RNE
  return (u16)(r >> 16);
}
__device__ __forceinline__ float bf2f(u32 hbits) {
  union { u32 u; float f; } v; v.u = hbits << 16;
  return v.f;
}

__device__ __forceinline__ void gl_lds16(const void* g, void* l) {
  __builtin_amdgcn_global_load_lds(
      (const __attribute__((address_space(1))) void*)g,
      (__attribute__((address_space(3))) void*)l,
      16, 0, 0);
}

// ---------------- cast fp32 -> bf16, vectorized ----------------------------
__global__ void __launch_bounds__(256) cast_bf16_kernel(
    const float* __restrict__ in, u16* __restrict__ out, int n4) {
  int i = blockIdx.x * 256 + threadIdx.x;
  if (i < n4) {
    float4 v = ((const float4*)in)[i];
    u16x4 o;
    o.x = f2bf(v.x); o.y = f2bf(v.y); o.z = f2bf(v.z); o.w = f2bf(v.w);
    ((u16x4*)out)[i] = o;
  }
}

// ---------------- fused rmsnorm + cast: one block per row ------------------
__global__ void __launch_bounds__(256) rmsnorm_cast_kernel(
    const float* __restrict__ x, const float* __restrict__ w, u16* __restrict__ h) {
  const int row = blockIdx.x;
  const int tid = threadIdx.x;
  const float4 v = ((const float4*)(x + (size_t)row * HID))[tid];
  float ss = v.x * v.x + v.y * v.y + v.z * v.z + v.w * v.w;
  #pragma unroll
  for (int m = 32; m >= 1; m >>= 1) ss += __shfl_xor(ss, m);
  __shared__ float sbuf[4];
  if ((tid & 63) == 0) sbuf[tid >> 6] = ss;
  __syncthreads();
  const float tot = sbuf[0] + sbuf[1] + sbuf[2] + sbuf[3];
  const float sc = rsqrtf(tot * (1.0f / HID) + 1e-6f);
  const float4 wv = ((const float4*)w)[tid];
  u16x4 o;
  o.x = f2bf(v.x * wv.x * sc);
  o.y = f2bf(v.y * wv.y * sc);
  o.z = f2bf(v.z * wv.z * sc);
  o.w = f2bf(v.w * wv.w * sc);
  ((u16x4*)(h + (size_t)row * HID))[tid] = o;
}

// ---------------- GEMM: C = A[M,K] @ W[N,K]^T (+epilogue) ------------------
// 128x128 block tile, BK=64, 256 threads = 4 waves (2x2), each wave 64x64
// via 4x4 grid of 16x16x32 bf16 MFMAs.
// Staging: global_load_lds w=16, LDS dest linear, global source column
// pre-swizzled with elem ^= (row&7)<<3 so the ds_read side can use the same
// XOR (rule 21: both-sides-or-neither). Double-buffered, counted vmcnt(8),
// raw s_barrier (no compiler vmcnt(0) drain).
// mode 0: out_bf[row*H+col] = bf16(acc + bias[col])
// mode 1: out_f [row*H+col] = xres[...] + (acc + bias[col]) * att[row*16 + col/64]
__global__ void __launch_bounds__(256) gemm_kernel(
    const u16* __restrict__ A, const u16* __restrict__ W,
    const float* __restrict__ bias,
    u16* __restrict__ out_bf,
    const float* __restrict__ att, const float* __restrict__ xres,
    float* __restrict__ out_f, int mode) {
  __shared__ u16 As[2][128 * 64];
  __shared__ u16 Bs[2][128 * 64];

  const int tid  = threadIdx.x;
  const int wid  = tid >> 6;
  const int lane = tid & 63;
  const int l15  = lane & 15;
  const int quad = lane >> 4;

  // XCD-aware remap (bijective; 4096 blocks, gridDim.x == 8):
  // the 8 column-blocks of one A row-panel get L values that are both
  // congruent mod 8 AND adjacent in /512-chunks -> co-XCD under either
  // round-robin or chunked XCD assignment; dispatched back-to-back so the
  // 256 KB A-panel is L2-resident for all 8.
  const int L    = blockIdx.y * 8 + blockIdx.x;
  const int xcd  = L & 7;
  const int j    = L >> 3;                       // 0..511
  const int rowBase = (xcd * 64 + (j >> 3)) * 128;
  const int colBase = (j & 7) * 128;

  const int wm = (wid >> 1) * 64;   // wave row offset in tile
  const int wn = (wid & 1) * 64;    // wave col offset in tile

  floatx4 acc[4][4];
  #pragma unroll
  for (int i = 0; i < 4; i++)
    #pragma unroll
    for (int jj = 0; jj < 4; jj++) acc[i][jj] = (floatx4){0.f, 0.f, 0.f, 0.f};

  // ---- staging: one 128x64 A-tile + 128x64 W-tile into buffer b ----
  // per wave: 8 global_load_lds instructions -> 8 vmcnt units per stage.
  #define STAGE(b, k0)                                                        \
    {                                                                         \
      _Pragma("unroll")                                                       \
      for (int t = 0; t < 4; t++) {                                           \
        const int e = wid * 2048 + t * 512 + lane * 8;                        \
        const int r = e >> 6;                                                 \
        const int c = (e & 63) ^ ((r & 7) << 3);  /* pre-swizzled source */   \
        gl_lds16(A + (size_t)(rowBase + r) * HID + ((k0) + c),                \
                 &As[b][wid * 2048 + t * 512]);                               \
        gl_lds16(W + (size_t)(colBase + r) * HID + ((k0) + c),                \
                 &Bs[b][wid * 2048 + t * 512]);                               \
      }                                                                       \
    }

  STAGE(0, 0);                       // prologue: tile 0 in flight
  int cur = 0;
  const int swz = (l15 & 7) << 3;    // read-side XOR (row&7)<<3 in elements

  for (int it = 0; it < 16; ++it) {
    if (it < 15) {
      STAGE(cur ^ 1, (it + 1) * 64); // issue next tile, stays in flight
      // oldest 8 outstanding = current tile's loads; any stray compiler
      // VMEM ops only inflate the wait (FIFO -> safe).
      asm volatile("s_waitcnt vmcnt(8)" ::: "memory");
    } else {
      asm volatile("s_waitcnt vmcnt(0)" ::: "memory");
    }
    __builtin_amdgcn_sched_barrier(0);
    __builtin_amdgcn_s_barrier();    // all waves' current-tile loads landed

    const u16* as = As[cur];
    const u16* bs = Bs[cur];
    #pragma unroll
    for (int kk = 0; kk < 64; kk += 32) {
      short8 af[4], bfr[4];
      const int cidx = (kk + quad * 8) ^ swz;    // swizzled column
      #pragma unroll
      for (int mt = 0; mt < 4; mt++)
        af[mt] = *(const short8*)&as[(wm + mt * 16 + l15) * 64 + cidx];
      #pragma unroll
      for (int nt = 0; nt < 4; nt++)
        bfr[nt] = *(const short8*)&bs[(wn + nt * 16 + l15) * 64 + cidx];
      #pragma unroll
      for (int mt = 0; mt < 4; mt++)
        #pragma unroll
        for (int nt = 0; nt < 4; nt++)
          acc[mt][nt] = __builtin_amdgcn_mfma_f32_16x16x32_bf16(
              af[mt], bfr[nt], acc[mt][nt], 0, 0, 0);
    }
    __builtin_amdgcn_s_barrier();    // all waves done reading buf[cur]
    cur ^= 1;                        // before it is restaged next iter
  }
  #undef STAGE

  // epilogue — C/D layout: col = lane&15, row = quad*4 + reg  (guide §3)
  #pragma unroll
  for (int nt = 0; nt < 4; nt++) {
    const int col = colBase + wn + nt * 16 + l15;
    const float b = bias[col];
    #pragma unroll
    for (int mt = 0; mt < 4; mt++) {
      #pragma unroll
      for (int r = 0; r < 4; r++) {
        const int row = rowBase + wm + mt * 16 + quad * 4 + r;
        const float v = acc[mt][nt][r] + b;
        const size_t idx = (size_t)row * HID + col;
        if (mode == 0) {
          out_bf[idx] = f2bf(v);
        } else {
          const float a = att[(size_t)row * 16 + (col >> 6)];
          out_f[idx] = xres[idx] + v * a;
        }
      }
    }
  }
}

// ---------------- per-head cosine: one wave per row ------------------------
__global__ void __launch_bounds__(64) att_kernel(
    const u16* __restrict__ xq, const u16* __restrict__ yk,
    const int* __restrict__ rep, float* __restrict__ att) {
  const int n = blockIdx.x;
  const int lane = threadIdx.x;
  const u16* q = xq + (size_t)rep[n] * HID + lane * 16;
  const u16* k = yk + (size_t)n * HID + lane * 16;
  float dot = 0.f, qq = 0.f, kk = 0.f;
  #pragma unroll
  for (int j = 0; j < 2; j++) {
    const uint4 qv = ((const uint4*)q)[j];
    const uint4 kv = ((const uint4*)k)[j];
    const u32 qa[4] = {qv.x, qv.y, qv.z, qv.w};
    const u32 ka[4] = {kv.x, kv.y, kv.z, kv.w};
    #pragma unroll
    for (int i = 0; i < 4; i++) {
      const float a0 = bf2f(qa[i] & 0xffffu), a1 = bf2f(qa[i] >> 16);
      const float b0 = bf2f(ka[i] & 0xffffu), b1 = bf2f(ka[i] >> 16);
      dot += a0 * b0 + a1 * b1;
      qq  += a0 * a0 + a1 * a1;
      kk  += b0 * b0 + b1 * b1;
    }
  }
  dot += __shfl_xor(dot, 1); dot += __shfl_xor(dot, 2);
  qq  += __shfl_xor(qq, 1);  qq  += __shfl_xor(qq, 2);
  kk  += __shfl_xor(kk, 1);  kk  += __shfl_xor(kk, 2);
  if ((lane & 3) == 0) {
    const float qn = fmaxf(sqrtf(qq), 1e-6f);
    const float kn = fmaxf(sqrtf(kk), 1e-6f);
    att[(size_t)n * 16 + (lane >> 2)] = dot / (qn * kn);
  }
}

// ---------------------------------------------------------------------------
extern "C" void kernel_launch(void* const* d_in, const int* in_sizes, int n_in,
                              void* d_out, int out_size, void* d_ws, size_t ws_size,
                              hipStream_t stream) {
  const float* x   = (const float*)d_in[0];
  const float* y   = (const float*)d_in[1];
  const int*   rep = (const int*)d_in[2];
  const float* lnw = (const float*)d_in[3];
  const float* qw  = (const float*)d_in[4];
  const float* qb  = (const float*)d_in[5];
  const float* kw  = (const float*)d_in[6];
  const float* kb  = (const float*)d_in[7];
  const float* vw  = (const float*)d_in[8];
  const float* vb  = (const float*)d_in[9];
  float* out = (float*)d_out;

  const size_t NH = (size_t)NROW * HID;
  const size_t WW = (size_t)HID * HID;

  // ws layout: y_bf16 | h/y_k bf16 | 3 weights bf16 | att f32 [| x_q bf16]
  u16*  y_bf  = (u16*)d_ws;          // NH
  u16*  hk_bf = y_bf + NH;           // NH  (h for Q-GEMM, then overwritten by y_k)
  u16*  w_q   = hk_bf + NH;          // WW
  u16*  w_k   = w_q + WW;
  u16*  w_v   = w_k + WW;
  float* att  = (float*)(w_v + WW);  // NROW*16
  const size_t base_need = (2 * NH + 3 * WW) * sizeof(u16) + (size_t)NROW * 16 * sizeof(float);
  u16* xq_bf;
  if (ws_size >= base_need + NH * sizeof(u16))
    xq_bf = (u16*)(att + (size_t)NROW * 16);
  else
    xq_bf = (u16*)d_out;  // front half of out buffer; dead before final overwrite

  cast_bf16_kernel<<<(int)(WW / 4 / 256), 256, 0, stream>>>(qw, w_q, (int)(WW / 4));
  cast_bf16_kernel<<<(int)(WW / 4 / 256), 256, 0, stream>>>(kw, w_k, (int)(WW / 4));
  cast_bf16_kernel<<<(int)(WW / 4 / 256), 256, 0, stream>>>(vw, w_v, (int)(WW / 4));
  cast_bf16_kernel<<<(int)(NH / 4 / 256), 256, 0, stream>>>(y, y_bf, (int)(NH / 4));
  rmsnorm_cast_kernel<<<NROW, 256, 0, stream>>>(x, lnw, hk_bf);

  dim3 grid(HID / 128, NROW / 128), block(256);
  // x_q = h @ q_w^T + q_b   (bf16 out)
  gemm_kernel<<<grid, block, 0, stream>>>(hk_bf, w_q, qb, xq_bf, nullptr, nullptr, nullptr, 0);
  // y_k = y @ k_w^T + k_b   (bf16 out, overwrites dead h)
  gemm_kernel<<<grid, block, 0, stream>>>(y_bf, w_k, kb, hk_bf, nullptr, nullptr, nullptr, 0);
  // att[n, head] = cos(q_gather, k)
  att_kernel<<<NROW, 64, 0, stream>>>(xq_bf, hk_bf, rep, att);
  // out = x + (y @ v_w^T + v_b) * att
  gemm_kernel<<<grid, block, 0, stream>>>(y_bf, w_v, vb, nullptr, att, x, out, 1);
}